// Round 15
// baseline (284.915 us; speedup 1.0000x reference)
//
#include <hip/hip_runtime.h>
#include <hip/hip_bf16.h>

// B=8, T=2048, C=384, H=6, Dh=64
constexpr int T_ = 2048;
constexpr int C_ = 384;
constexpr int H_ = 6;
constexpr int D_ = 64;

typedef unsigned int u32;
typedef unsigned short u16;
typedef __attribute__((ext_vector_type(4))) float f32x4;
typedef __attribute__((ext_vector_type(16))) float f32x16;
typedef __attribute__((ext_vector_type(8))) short bf16x8;
typedef __attribute__((ext_vector_type(4))) short bf16x4;

__device__ __forceinline__ u32 f2bf(float f) {
  u32 u = __float_as_uint(f);
  return (u + 0x7FFFu + ((u >> 16) & 1u)) >> 16;  // RNE
}
__device__ __forceinline__ u32 pk2(float a, float b) {
  return f2bf(a) | (f2bf(b) << 16);
}
__device__ __forceinline__ float bflo(u32 u) { return __uint_as_float(u << 16); }
__device__ __forceinline__ float bfhi(u32 u) { return __uint_as_float(u & 0xFFFF0000u); }
__device__ __forceinline__ float bfr(float v) {  // bf16-rounded f32 (symmetry)
  return __uint_as_float(f2bf(v) << 16);
}
// packed f32->bf16x2 (v_cvt_pk_bf16_f32)
__device__ __forceinline__ u32 pkcvt(float a, float b) {
  __hip_bfloat162 h = __float22bfloat162_rn(float2{a, b});
  return *(u32*)&h;
}
// async global->LDS DMA, 16B per lane; lds dest = wave-uniform base + lane*16
__device__ __forceinline__ void gload16(const u16* g, u16* l) {
  __builtin_amdgcn_global_load_lds(
      (const __attribute__((address_space(1))) u32*)g,
      (__attribute__((address_space(3))) u32*)l, 16, 0, 0);
}

constexpr float SC_ = 0.18033688011112042f;  // 0.125 * log2(e)

// Job tables (LPT, per-bh 24 jobs, rank-major dispatch): qb>=8 split in two
// k-chunks (fixed-max softmax => partials are associative sums).
__device__ const int JQB[24] = {15,15, 7,14,14,13,13, 6,12,12,11,11, 5,10,10, 9, 9, 4, 8, 8, 3, 2, 1, 0};
__device__ const int JK0[24] = { 0,16, 0, 0,15, 0,14, 0, 0,13, 0,12, 0, 0,11, 0,10, 0, 0, 9, 0, 0, 0, 0};
__device__ const int JKN[24] = {16,32,16,15,30,14,28,14,13,26,12,24,12,11,22,10,20,10, 9,18, 8, 6, 4, 2};

// ---------------------------------------------------------------------------
// x fp32 -> bf16 row-major [16384][384]
// ---------------------------------------------------------------------------
__global__ __launch_bounds__(256) void xcvt_kernel(
    const float* __restrict__ x, u16* __restrict__ xb) {
  const int id = blockIdx.x * 256 + threadIdx.x;  // 786432 threads x 8 elems
  const float* s = x + (size_t)id * 8;
  f32x4 a = *(const f32x4*)s, b = *(const f32x4*)(s + 4);
  uint4 o;
  o.x = pkcvt(a[0], a[1]); o.y = pkcvt(a[2], a[3]);
  o.z = pkcvt(b[0], b[1]); o.w = pkcvt(b[2], b[3]);
  *(uint4*)(xb + (size_t)id * 8) = o;
}

// ---------------------------------------------------------------------------
// Weights -> bf16 transposed [n][k]
// ---------------------------------------------------------------------------
__global__ __launch_bounds__(256) void convert_kernel(
    const float* __restrict__ Wq, const float* __restrict__ Wk,
    const float* __restrict__ Wv, const float* __restrict__ Wp,
    u16* __restrict__ Wt, u16* __restrict__ Wpt) {
  int id = blockIdx.x * 256 + threadIdx.x;
  if (id < 110592) {                       // Wt: 1152*384/4
    int n = id / 96, c0 = (id % 96) * 4;
    int mat = n / 384, nn = n % 384, h = nn >> 6, d = nn & 63;
    const float* W = (mat == 0) ? Wq : ((mat == 1) ? Wk : Wv);
    const float* s = W + (size_t)(h * C_ + c0) * D_ + d;
    uint2 o; o.x = pk2(s[0], s[64]); o.y = pk2(s[128], s[192]);
    *(uint2*)&Wt[(size_t)n * 384 + c0] = o;
  } else {                                 // Wpt: 384*384/4
    int id2 = id - 110592;
    int n = id2 / 96, c0 = (id2 % 96) * 4;
    const float* s = Wp + (size_t)c0 * C_ + n;
    uint2 o; o.x = pk2(s[0], s[384]); o.y = pk2(s[768], s[1152]);
    *(uint2*)&Wpt[(size_t)n * 384 + c0] = o;
  }
}

// ===========================================================================
// m97-structure 128x128 bf16 GEMM core (HW-proven 874 TF on gfx950)
// ===========================================================================
#define GEMM_BODY(A_PTR, B_PTR)                                                \
  __shared__ u16 As[128 * 64], Bs[128 * 64];                                   \
  const int tid = threadIdx.x;                                                 \
  const int l = tid & 63, w = tid >> 6;                                        \
  const int wr = w >> 1, wc = w & 1;                                           \
  const int ql = l & 15, g = l >> 4;                                           \
  const int rc = l >> 3;   /* row within an 8-row DMA call */                  \
  const int sgr = l & 7;   /* LDS slot granule this lane fills */              \
  f32x4 acc[4][4];                                                             \
  _Pragma("unroll") for (int fi = 0; fi < 4; ++fi)                             \
  _Pragma("unroll") for (int fj = 0; fj < 4; ++fj) acc[fi][fj] = (f32x4)0.f;   \
  for (int kc = 0; kc < 6; ++kc) {                                             \
    if (kc) __syncthreads();                                                   \
    _Pragma("unroll") for (int c = 0; c < 4; ++c) {                            \
      const int rbase = w * 32 + c * 8;                                        \
      const int row = rbase + rc;                                              \
      const int gcol = (sgr ^ (row & 7)) * 8; /* inverse-swizzled source */    \
      gload16((A_PTR) + (size_t)(m0 + row) * 384 + kc * 64 + gcol,             \
              &As[rbase * 64]);                                                \
      gload16((B_PTR) + (size_t)(n0 + row) * 384 + kc * 64 + gcol,             \
              &Bs[rbase * 64]);                                                \
    }                                                                          \
    __syncthreads(); /* compiler drains vmcnt before barrier */                \
    __builtin_amdgcn_s_setprio(1);                                             \
    _Pragma("unroll") for (int ks = 0; ks < 2; ++ks) {                         \
      bf16x8 af[4], bfr_[4];                                                   \
      const int gl = ks * 4 + g;                                               \
      const int slot8 = (gl ^ (ql & 7)) * 8;                                   \
      _Pragma("unroll") for (int fi = 0; fi < 4; ++fi)                         \
        af[fi] = *(const bf16x8*)&As[(wr * 64 + fi * 16 + ql) * 64 + slot8];   \
      _Pragma("unroll") for (int fj = 0; fj < 4; ++fj)                         \
        bfr_[fj] = *(const bf16x8*)&Bs[(wc * 64 + fj * 16 + ql) * 64 + slot8]; \
      _Pragma("unroll") for (int fi = 0; fi < 4; ++fi)                         \
      _Pragma("unroll") for (int fj = 0; fj < 4; ++fj)                         \
        acc[fi][fj] = __builtin_amdgcn_mfma_f32_16x16x32_bf16(                 \
            af[fi], bfr_[fj], acc[fi][fj], 0, 0, 0);                           \
    }                                                                          \
    __builtin_amdgcn_s_setprio(0);                                             \
  }

// ---------------------------------------------------------------------------
// QKV GEMM: xb [16384][384] @ Wt [1152][384] -> Qb/Kb [B,H,T,D], Vtb [B,H,D,T]
// ---------------------------------------------------------------------------
__global__ __launch_bounds__(256) void gemm_qkv(
    const u16* __restrict__ xb, const u16* __restrict__ Wt,
    u16* __restrict__ Qb, u16* __restrict__ Kb, u16* __restrict__ Vtb) {
  const int bx = blockIdx.x;
  const int mt = bx / 9, nt = bx % 9;
  const int m0 = mt * 128, n0 = nt * 128;

  GEMM_BODY(xb, Wt)

  const int mat = nt / 3;
#pragma unroll
  for (int fi = 0; fi < 4; ++fi) {
    const int m = m0 + wr * 64 + fi * 16 + g * 4;
    const int b = m >> 11, t = m & 2047;
#pragma unroll
    for (int fj = 0; fj < 4; ++fj) {
      const int n = n0 + wc * 64 + fj * 16 + ql;
      const int nn = n - mat * 384, h = nn >> 6, d = nn & 63;
      if (mat == 0) {
        u16* dst = Qb + ((size_t)(b * H_ + h) * T_ + t) * D_ + d;
#pragma unroll
        for (int r = 0; r < 4; ++r)
          dst[(size_t)r * D_] = (u16)f2bf(acc[fi][fj][r] * SC_);
      } else if (mat == 1) {
        u16* dst = Kb + ((size_t)(b * H_ + h) * T_ + t) * D_ + d;
#pragma unroll
        for (int r = 0; r < 4; ++r) dst[(size_t)r * D_] = (u16)f2bf(acc[fi][fj][r]);
      } else {  // V transposed [B,H,D,T]
        u16* dst = Vtb + ((size_t)(b * H_ + h) * D_ + d) * T_ + t;
        uint2 o;
        o.x = pkcvt(acc[fi][fj][0], acc[fi][fj][1]);
        o.y = pkcvt(acc[fi][fj][2], acc[fi][fj][3]);
        *(uint2*)dst = o;
      }
    }
  }
}

// ---------------------------------------------------------------------------
// Output projection GEMM: attnb [16384][384] @ Wpt [384][384] + bp -> out fp32
// ---------------------------------------------------------------------------
__global__ __launch_bounds__(256) void gemm_proj(
    const u16* __restrict__ attnb, const u16* __restrict__ Wpt,
    const float* __restrict__ bp, float* __restrict__ out) {
  const int bx = blockIdx.x;
  const int mt = bx / 3, nt = bx % 3;
  const int m0 = mt * 128, n0 = nt * 128;

  GEMM_BODY(attnb, Wpt)

#pragma unroll
  for (int fj = 0; fj < 4; ++fj) {
    const int n = n0 + wc * 64 + fj * 16 + ql;
    const float bias = bp[n];
#pragma unroll
    for (int fi = 0; fi < 4; ++fi) {
      const int m = m0 + wr * 64 + fi * 16 + g * 4;
#pragma unroll
      for (int r = 0; r < 4; ++r)
        out[(size_t)(m + r) * C_ + n] = acc[fi][fj][r] + bias;
    }
  }
}

// ---------------------------------------------------------------------------
// Flash attention, split-K balanced jobs (max 16 k-tiles; uniform-ish LPT).
// Fixed-max softmax => partial (O_unnorm, l) sums are associative across
// k-chunks. Two-slot ticket combine: half0's slot IS its attnb slice
// (unnormalized bf16), half1's slot is Opart; write-own -> threadfence ->
// atomicAdd ticket; second finisher reads other slot, adds own bf16-rounded
// values (symmetric => deterministic), normalizes, writes attnb.
// ---------------------------------------------------------------------------
__global__ __launch_bounds__(256) void attn_mfma_kernel(
    const u16* __restrict__ Qb, const u16* __restrict__ Kb,
    const u16* __restrict__ Vtb, u16* __restrict__ attnb,
    u16* __restrict__ Opart, float* __restrict__ lpart,
    int* __restrict__ flags) {
  __shared__ u16 Ks[2][64 * 64];
  __shared__ u16 Vs[2][64 * 64];
  const int tid = threadIdx.x;
  const int bx = blockIdx.x;
  const int rank = bx / 48;                // LPT: big jobs dispatch first
  const int bh = bx % 48;
  const int qb = JQB[rank];
  const int jk0 = JK0[rank], jkn = JKN[rank];
  const bool is_split = (qb >= 8);
  const int h = bh % H_, b = bh / H_;
  const int Q0 = qb * 128;
  const size_t hb = (size_t)bh * T_ * D_;

  const int l = tid & 63, w = tid >> 6;
  const int hi = l >> 5, l31 = l & 31;
  const int qw0 = Q0 + w * 32;
  const int qrow = qw0 + l31;
  const int qwmax = qw0 + 31;
  const int rc = l >> 3;   // row within an 8-row DMA call
  const int sgr = l & 7;   // LDS granule this lane fills

  bf16x8 qf[4];
  {
    const u16* qg = Qb + hb + (size_t)qrow * D_ + hi * 8;
#pragma unroll
    for (int cs = 0; cs < 4; ++cs) qf[cs] = *(const bf16x8*)(qg + cs * 16);
  }

  // prologue: DMA tile jk0 -> buf 0
#pragma unroll
  for (int c = 0; c < 2; ++c) {
    const int rbase = w * 16 + c * 8;
    const int row = rbase + rc;
    const int gc = (sgr ^ (row & 7)) * 8;
    gload16(Kb + hb + (size_t)(jk0 * 64 + row) * D_ + gc, &Ks[0][rbase * 64]);
    gload16(Vtb + hb + (size_t)row * T_ + jk0 * 64 + gc, &Vs[0][rbase * 64]);
  }
  __syncthreads();

  f32x16 oacc[2];
  oacc[0] = (f32x16)0.f; oacc[1] = (f32x16)0.f;
  float lrun = 0.f;
  const int swzA = (l31 & 7) * 8;

  for (int jt = jk0; jt < jkn; ++jt) {
    const int jj = jt - jk0;
    const int cur = jj & 1;
    if (jt + 1 < jkn) {  // async DMA next tile into the other buffer
      const int nb = cur ^ 1;
#pragma unroll
      for (int c = 0; c < 2; ++c) {
        const int rbase = w * 16 + c * 8;
        const int row = rbase + rc;
        const int gc = (sgr ^ (row & 7)) * 8;
        gload16(Kb + hb + (size_t)((jt + 1) * 64 + row) * D_ + gc,
                &Ks[nb][rbase * 64]);
        gload16(Vtb + hb + (size_t)row * T_ + (jt + 1) * 64 + gc,
                &Vs[nb][rbase * 64]);
      }
    }

    if (jt * 64 <= qwmax) {
      // ---- S phase (scores in log2 domain; Q pre-scaled) ----
      f32x16 sacc[2];
      sacc[0] = (f32x16)0.f; sacc[1] = (f32x16)0.f;
      __builtin_amdgcn_s_setprio(1);
#pragma unroll
      for (int kc = 0; kc < 2; ++kc)
#pragma unroll
        for (int cs = 0; cs < 4; ++cs) {
          bf16x8 kf = *(const bf16x8*)
              &Ks[cur][(kc * 32 + l31) * 64 + ((cs * 16 + 8 * hi) ^ swzA)];
          sacc[kc] = __builtin_amdgcn_mfma_f32_32x32x16_bf16(kf, qf[cs], sacc[kc], 0, 0, 0);
        }
      __builtin_amdgcn_s_setprio(0);

      // ---- softmax-lite: P = exp2(s), fixed max ----
      float ps[32];
      if ((jt + 1) * 64 > qw0) {  // diagonal region: element mask
#pragma unroll
        for (int kc = 0; kc < 2; ++kc)
#pragma unroll
          for (int r = 0; r < 16; ++r) {
            const int kglob = jt * 64 + kc * 32 + (r & 3) + 8 * (r >> 2) + 4 * hi;
            ps[kc * 16 + r] = __builtin_amdgcn_exp2f(
                kglob > qrow ? -1e30f : sacc[kc][r]);
          }
      } else {
#pragma unroll
        for (int kc = 0; kc < 2; ++kc)
#pragma unroll
          for (int r = 0; r < 16; ++r)
            ps[kc * 16 + r] = __builtin_amdgcn_exp2f(sacc[kc][r]);
      }

      // tree sum
      float sm[16];
#pragma unroll
      for (int i = 0; i < 16; ++i) sm[i] = ps[i] + ps[i + 16];
#pragma unroll
      for (int i = 0; i < 8; ++i) sm[i] = sm[i] + sm[i + 8];
#pragma unroll
      for (int i = 0; i < 4; ++i) sm[i] = sm[i] + sm[i + 4];
      float rs = (sm[0] + sm[1]) + (sm[2] + sm[3]);
      rs += __shfl_xor(rs, 32);
      lrun += rs;

      // P -> bf16 B-frags, register-local
      u32 pw[4][4];
#pragma unroll
      for (int ks = 0; ks < 4; ++ks)
#pragma unroll
        for (int wd = 0; wd < 4; ++wd)
          pw[ks][wd] = pkcvt(ps[(ks >> 1) * 16 + (ks & 1) * 8 + 2 * wd],
                             ps[(ks >> 1) * 16 + (ks & 1) * 8 + 2 * wd + 1]);

      // ---- O phase ----
      __builtin_amdgcn_s_setprio(1);
#pragma unroll
      for (int dc = 0; dc < 2; ++dc) {
#pragma unroll
        for (int ks = 0; ks < 4; ++ks) {
          const int rb = (dc * 32 + l31) * 64;
          bf16x4 v0 = *(const bf16x4*)&Vs[cur][rb + ((ks * 16 + 4 * hi) ^ swzA)];
          bf16x4 v1 = *(const bf16x4*)&Vs[cur][rb + ((ks * 16 + 4 * hi + 8) ^ swzA)];
          bf16x8 vf;
          *(bf16x4*)&vf = v0; *((bf16x4*)&vf + 1) = v1;
          bf16x8 pf;
          *(uint4*)&pf = make_uint4(pw[ks][0], pw[ks][1], pw[ks][2], pw[ks][3]);
          oacc[dc] = __builtin_amdgcn_mfma_f32_32x32x16_bf16(vf, pf, oacc[dc], 0, 0, 0);
        }
      }
      __builtin_amdgcn_s_setprio(0);
    }

    __syncthreads();  // compute(jt) done everywhere + DMA(jt+1) drained
  }

  u16* obase = attnb + ((size_t)(b * T_ + qrow)) * C_ + h * 64;

  if (!is_split) {
    const float inv = 1.0f / lrun;
#pragma unroll
    for (int dc = 0; dc < 2; ++dc)
#pragma unroll
      for (int g4 = 0; g4 < 4; ++g4) {
        uint2 o;
        o.x = pkcvt(oacc[dc][g4 * 4 + 0] * inv, oacc[dc][g4 * 4 + 1] * inv);
        o.y = pkcvt(oacc[dc][g4 * 4 + 2] * inv, oacc[dc][g4 * 4 + 3] * inv);
        *(uint2*)(obase + dc * 32 + 8 * g4 + 4 * hi) = o;
      }
  } else {
    const int qt = bh * 8 + (qb - 8);
    const int halfid = (jk0 > 0) ? 1 : 0;
    const int qloc = w * 32 + l31;
    u16* mypart = halfid ? (Opart + ((size_t)qt * 128 + qloc) * 64) : obase;
    // 1) store own unnormalized bf16 partial to own slot
#pragma unroll
    for (int dc = 0; dc < 2; ++dc)
#pragma unroll
      for (int g4 = 0; g4 < 4; ++g4) {
        uint2 o;
        o.x = pkcvt(oacc[dc][g4 * 4 + 0], oacc[dc][g4 * 4 + 1]);
        o.y = pkcvt(oacc[dc][g4 * 4 + 2], oacc[dc][g4 * 4 + 3]);
        *(uint2*)(mypart + dc * 32 + 8 * g4 + 4 * hi) = o;
      }
    if (hi == 0) lpart[(qt * 2 + halfid) * 128 + qloc] = lrun;
    __threadfence();
    __syncthreads();
    __shared__ int dec;
    if (tid == 0) dec = atomicAdd(&flags[qt], 1);
    __syncthreads();
    if (dec == 1) {  // second finisher combines (order-independent math)
      __threadfence();
      const u16* otherO =
          halfid ? obase : (Opart + ((size_t)qt * 128 + qloc) * 64);
      const float lo = lpart[(qt * 2 + (halfid ^ 1)) * 128 + qloc];
      const float inv = 1.0f / (lrun + lo);
#pragma unroll
      for (int dc = 0; dc < 2; ++dc)
#pragma unroll
        for (int g4 = 0; g4 < 4; ++g4) {
          uint2 ov = *(const uint2*)(otherO + dc * 32 + 8 * g4 + 4 * hi);
          const float s0 = bfr(oacc[dc][g4 * 4 + 0]) + bflo(ov.x);
          const float s1 = bfr(oacc[dc][g4 * 4 + 1]) + bfhi(ov.x);
          const float s2 = bfr(oacc[dc][g4 * 4 + 2]) + bflo(ov.y);
          const float s3 = bfr(oacc[dc][g4 * 4 + 3]) + bfhi(ov.y);
          uint2 o;
          o.x = pkcvt(s0 * inv, s1 * inv);
          o.y = pkcvt(s2 * inv, s3 * inv);
          *(uint2*)(obase + dc * 32 + 8 * g4 + 4 * hi) = o;
        }
    }
  }
}

// ---------------------------------------------------------------------------
extern "C" void kernel_launch(void* const* d_in, const int* in_sizes, int n_in,
                              void* d_out, int out_size, void* d_ws, size_t ws_size,
                              hipStream_t stream) {
  (void)in_sizes; (void)n_in; (void)out_size; (void)ws_size;
  const float* x  = (const float*)d_in[0];
  const float* Wq = (const float*)d_in[1];
  const float* Wk = (const float*)d_in[2];
  const float* Wv = (const float*)d_in[3];
  const float* Wp = (const float*)d_in[4];
  const float* bp = (const float*)d_in[5];
  float* out = (float*)d_out;

  // ws (u16 units): Wt | Wpt | Qb | Kb | Vtb | R (xb then attnb, disjoint
  // lifetimes) | Opart (half1 split partials) | lpart (f32) | flags (int).
  // Total ~59.4 MB (< 64.1 MB proven envelope from R1).
  u16* Wt    = (u16*)d_ws;
  u16* Wpt   = Wt + 442368;
  u16* Qb    = Wpt + 147456;
  u16* Kb    = Qb + 6291456;
  u16* Vtb   = Kb + 6291456;
  u16* R     = Vtb + 6291456;
  u16* xb    = R;
  u16* attnb = R;
  u16* Opart = R + 6291456;                 // 384*128*64 u16
  float* lpart = (float*)(Opart + 3145728); // 384*2*128 f32
  int* flags = (int*)(lpart + 98304);       // 384 ints

  hipMemsetAsync(flags, 0, 384 * sizeof(int), stream);
  xcvt_kernel<<<3072, 256, 0, stream>>>(x, xb);
  convert_kernel<<<576, 256, 0, stream>>>(Wq, Wk, Wv, Wp, Wt, Wpt);
  gemm_qkv<<<1152, 256, 0, stream>>>(xb, Wt, Qb, Kb, Vtb);
  attn_mfma_kernel<<<1152, 256, 0, stream>>>(Qb, Kb, Vtb, attnb, Opart, lpart, flags);
  gemm_proj<<<384, 256, 0, stream>>>(attnb, Wpt, bp, out);
}

// Round 17
// 121.352 us; speedup vs baseline: 2.3478x; 2.3478x over previous
//
#include <hip/hip_runtime.h>
#include <hip/hip_bf16.h>

// B=8, T=2048, C=384, H=6, Dh=64
constexpr int T_ = 2048;
constexpr int C_ = 384;
constexpr int H_ = 6;
constexpr int D_ = 64;

typedef unsigned int u32;
typedef unsigned short u16;
typedef __attribute__((ext_vector_type(4))) float f32x4;
typedef __attribute__((ext_vector_type(16))) float f32x16;
typedef __attribute__((ext_vector_type(8))) short bf16x8;
typedef __attribute__((ext_vector_type(4))) short bf16x4;

__device__ __forceinline__ u32 f2bf(float f) {
  u32 u = __float_as_uint(f);
  return (u + 0x7FFFu + ((u >> 16) & 1u)) >> 16;  // RNE
}
__device__ __forceinline__ u32 pk2(float a, float b) {
  return f2bf(a) | (f2bf(b) << 16);
}
__device__ __forceinline__ float bflo(u32 u) { return __uint_as_float(u << 16); }
__device__ __forceinline__ float bfhi(u32 u) { return __uint_as_float(u & 0xFFFF0000u); }
// packed f32->bf16x2 (v_cvt_pk_bf16_f32)
__device__ __forceinline__ u32 pkcvt(float a, float b) {
  __hip_bfloat162 h = __float22bfloat162_rn(float2{a, b});
  return *(u32*)&h;
}
// async global->LDS DMA, 16B per lane; lds dest = wave-uniform base + lane*16
__device__ __forceinline__ void gload16(const u16* g, u16* l) {
  __builtin_amdgcn_global_load_lds(
      (const __attribute__((address_space(1))) u32*)g,
      (__attribute__((address_space(3))) u32*)l, 16, 0, 0);
}

constexpr float SC_ = 0.18033688011112042f;  // 0.125 * log2(e)

// Job tables (LPT, per-bh 24 jobs, rank-major dispatch): qb>=8 split in two
// k-chunks (fixed-max softmax => partials are associative sums).
__device__ const int JQB[24] = {15,15, 7,14,14,13,13, 6,12,12,11,11, 5,10,10, 9, 9, 4, 8, 8, 3, 2, 1, 0};
__device__ const int JK0[24] = { 0,16, 0, 0,15, 0,14, 0, 0,13, 0,12, 0, 0,11, 0,10, 0, 0, 9, 0, 0, 0, 0};
__device__ const int JKN[24] = {16,32,16,15,30,14,28,14,13,26,12,24,12,11,22,10,20,10, 9,18, 8, 6, 4, 2};

// ---------------------------------------------------------------------------
// x fp32 -> bf16 row-major [16384][384]
// ---------------------------------------------------------------------------
__global__ __launch_bounds__(256) void xcvt_kernel(
    const float* __restrict__ x, u16* __restrict__ xb) {
  const int id = blockIdx.x * 256 + threadIdx.x;  // 786432 threads x 8 elems
  const float* s = x + (size_t)id * 8;
  f32x4 a = *(const f32x4*)s, b = *(const f32x4*)(s + 4);
  uint4 o;
  o.x = pkcvt(a[0], a[1]); o.y = pkcvt(a[2], a[3]);
  o.z = pkcvt(b[0], b[1]); o.w = pkcvt(b[2], b[3]);
  *(uint4*)(xb + (size_t)id * 8) = o;
}

// ---------------------------------------------------------------------------
// Weights -> bf16 transposed [n][k]
// ---------------------------------------------------------------------------
__global__ __launch_bounds__(256) void convert_kernel(
    const float* __restrict__ Wq, const float* __restrict__ Wk,
    const float* __restrict__ Wv, const float* __restrict__ Wp,
    u16* __restrict__ Wt, u16* __restrict__ Wpt) {
  int id = blockIdx.x * 256 + threadIdx.x;
  if (id < 110592) {                       // Wt: 1152*384/4
    int n = id / 96, c0 = (id % 96) * 4;
    int mat = n / 384, nn = n % 384, h = nn >> 6, d = nn & 63;
    const float* W = (mat == 0) ? Wq : ((mat == 1) ? Wk : Wv);
    const float* s = W + (size_t)(h * C_ + c0) * D_ + d;
    uint2 o; o.x = pk2(s[0], s[64]); o.y = pk2(s[128], s[192]);
    *(uint2*)&Wt[(size_t)n * 384 + c0] = o;
  } else {                                 // Wpt: 384*384/4
    int id2 = id - 110592;
    int n = id2 / 96, c0 = (id2 % 96) * 4;
    const float* s = Wp + (size_t)c0 * C_ + n;
    uint2 o; o.x = pk2(s[0], s[384]); o.y = pk2(s[768], s[1152]);
    *(uint2*)&Wpt[(size_t)n * 384 + c0] = o;
  }
}

// ===========================================================================
// m97-structure 128x128 bf16 GEMM core (HW-proven 874 TF on gfx950)
// ===========================================================================
#define GEMM_BODY(A_PTR, B_PTR)                                                \
  __shared__ u16 As[128 * 64], Bs[128 * 64];                                   \
  const int tid = threadIdx.x;                                                 \
  const int l = tid & 63, w = tid >> 6;                                        \
  const int wr = w >> 1, wc = w & 1;                                           \
  const int ql = l & 15, g = l >> 4;                                           \
  const int rc = l >> 3;   /* row within an 8-row DMA call */                  \
  const int sgr = l & 7;   /* LDS slot granule this lane fills */              \
  f32x4 acc[4][4];                                                             \
  _Pragma("unroll") for (int fi = 0; fi < 4; ++fi)                             \
  _Pragma("unroll") for (int fj = 0; fj < 4; ++fj) acc[fi][fj] = (f32x4)0.f;   \
  for (int kc = 0; kc < 6; ++kc) {                                             \
    if (kc) __syncthreads();                                                   \
    _Pragma("unroll") for (int c = 0; c < 4; ++c) {                            \
      const int rbase = w * 32 + c * 8;                                        \
      const int row = rbase + rc;                                              \
      const int gcol = (sgr ^ (row & 7)) * 8; /* inverse-swizzled source */    \
      gload16((A_PTR) + (size_t)(m0 + row) * 384 + kc * 64 + gcol,             \
              &As[rbase * 64]);                                                \
      gload16((B_PTR) + (size_t)(n0 + row) * 384 + kc * 64 + gcol,             \
              &Bs[rbase * 64]);                                                \
    }                                                                          \
    __syncthreads(); /* compiler drains vmcnt before barrier */                \
    __builtin_amdgcn_s_setprio(1);                                             \
    _Pragma("unroll") for (int ks = 0; ks < 2; ++ks) {                         \
      bf16x8 af[4], bfr_[4];                                                   \
      const int gl = ks * 4 + g;                                               \
      const int slot8 = (gl ^ (ql & 7)) * 8;                                   \
      _Pragma("unroll") for (int fi = 0; fi < 4; ++fi)                         \
        af[fi] = *(const bf16x8*)&As[(wr * 64 + fi * 16 + ql) * 64 + slot8];   \
      _Pragma("unroll") for (int fj = 0; fj < 4; ++fj)                         \
        bfr_[fj] = *(const bf16x8*)&Bs[(wc * 64 + fj * 16 + ql) * 64 + slot8]; \
      _Pragma("unroll") for (int fi = 0; fi < 4; ++fi)                         \
      _Pragma("unroll") for (int fj = 0; fj < 4; ++fj)                         \
        acc[fi][fj] = __builtin_amdgcn_mfma_f32_16x16x32_bf16(                 \
            af[fi], bfr_[fj], acc[fi][fj], 0, 0, 0);                           \
    }                                                                          \
    __builtin_amdgcn_s_setprio(0);                                             \
  }

// ---------------------------------------------------------------------------
// QKV GEMM: xb [16384][384] @ Wt [1152][384] -> Qb/Kb [B,H,T,D], Vtb [B,H,D,T]
// ---------------------------------------------------------------------------
__global__ __launch_bounds__(256) void gemm_qkv(
    const u16* __restrict__ xb, const u16* __restrict__ Wt,
    u16* __restrict__ Qb, u16* __restrict__ Kb, u16* __restrict__ Vtb) {
  const int bx = blockIdx.x;
  const int mt = bx / 9, nt = bx % 9;
  const int m0 = mt * 128, n0 = nt * 128;

  GEMM_BODY(xb, Wt)

  const int mat = nt / 3;
#pragma unroll
  for (int fi = 0; fi < 4; ++fi) {
    const int m = m0 + wr * 64 + fi * 16 + g * 4;
    const int b = m >> 11, t = m & 2047;
#pragma unroll
    for (int fj = 0; fj < 4; ++fj) {
      const int n = n0 + wc * 64 + fj * 16 + ql;
      const int nn = n - mat * 384, h = nn >> 6, d = nn & 63;
      if (mat == 0) {
        u16* dst = Qb + ((size_t)(b * H_ + h) * T_ + t) * D_ + d;
#pragma unroll
        for (int r = 0; r < 4; ++r)
          dst[(size_t)r * D_] = (u16)f2bf(acc[fi][fj][r] * SC_);
      } else if (mat == 1) {
        u16* dst = Kb + ((size_t)(b * H_ + h) * T_ + t) * D_ + d;
#pragma unroll
        for (int r = 0; r < 4; ++r) dst[(size_t)r * D_] = (u16)f2bf(acc[fi][fj][r]);
      } else {  // V transposed [B,H,D,T]
        u16* dst = Vtb + ((size_t)(b * H_ + h) * D_ + d) * T_ + t;
        uint2 o;
        o.x = pkcvt(acc[fi][fj][0], acc[fi][fj][1]);
        o.y = pkcvt(acc[fi][fj][2], acc[fi][fj][3]);
        *(uint2*)dst = o;
      }
    }
  }
}

// ---------------------------------------------------------------------------
// Output projection GEMM: attnb [16384][384] @ Wpt [384][384] + bp -> out fp32
// ---------------------------------------------------------------------------
__global__ __launch_bounds__(256) void gemm_proj(
    const u16* __restrict__ attnb, const u16* __restrict__ Wpt,
    const float* __restrict__ bp, float* __restrict__ out) {
  const int bx = blockIdx.x;
  const int mt = bx / 3, nt = bx % 3;
  const int m0 = mt * 128, n0 = nt * 128;

  GEMM_BODY(attnb, Wpt)

#pragma unroll
  for (int fj = 0; fj < 4; ++fj) {
    const int n = n0 + wc * 64 + fj * 16 + ql;
    const float bias = bp[n];
#pragma unroll
    for (int fi = 0; fi < 4; ++fi) {
      const int m = m0 + wr * 64 + fi * 16 + g * 4;
#pragma unroll
      for (int r = 0; r < 4; ++r)
        out[(size_t)(m + r) * C_ + n] = acc[fi][fj][r] + bias;
    }
  }
}

// ---------------------------------------------------------------------------
// Flash attention, split-K balanced jobs (max 16 k-tiles). Fixed-max softmax
// => partial (O_unnorm, l) sums are associative. Split blocks write ONLY
// their own slot (half0 -> its attnb slice, half1 -> Opart; both -> lpart)
// with plain stores. NO fences/atomics (threadfence on multi-XCD = L2
// writeback disaster, R15). The combine runs as a separate kernel: the
// kernel boundary IS the global sync.
// ---------------------------------------------------------------------------
__global__ __launch_bounds__(256) void attn_mfma_kernel(
    const u16* __restrict__ Qb, const u16* __restrict__ Kb,
    const u16* __restrict__ Vtb, u16* __restrict__ attnb,
    u16* __restrict__ Opart, float* __restrict__ lpart) {
  __shared__ u16 Ks[2][64 * 64];
  __shared__ u16 Vs[2][64 * 64];
  const int tid = threadIdx.x;
  const int bx = blockIdx.x;
  const int rank = bx / 48;                // LPT: big jobs dispatch first
  const int bh = bx % 48;
  const int qb = JQB[rank];
  const int jk0 = JK0[rank], jkn = JKN[rank];
  const bool is_split = (qb >= 8);
  const int h = bh % H_, b = bh / H_;
  const int Q0 = qb * 128;
  const size_t hb = (size_t)bh * T_ * D_;

  const int l = tid & 63, w = tid >> 6;
  const int hi = l >> 5, l31 = l & 31;
  const int qw0 = Q0 + w * 32;
  const int qrow = qw0 + l31;
  const int qwmax = qw0 + 31;
  const int rc = l >> 3;   // row within an 8-row DMA call
  const int sgr = l & 7;   // LDS granule this lane fills

  bf16x8 qf[4];
  {
    const u16* qg = Qb + hb + (size_t)qrow * D_ + hi * 8;
#pragma unroll
    for (int cs = 0; cs < 4; ++cs) qf[cs] = *(const bf16x8*)(qg + cs * 16);
  }

  // prologue: DMA tile jk0 -> buf 0
#pragma unroll
  for (int c = 0; c < 2; ++c) {
    const int rbase = w * 16 + c * 8;
    const int row = rbase + rc;
    const int gc = (sgr ^ (row & 7)) * 8;
    gload16(Kb + hb + (size_t)(jk0 * 64 + row) * D_ + gc, &Ks[0][rbase * 64]);
    gload16(Vtb + hb + (size_t)row * T_ + jk0 * 64 + gc, &Vs[0][rbase * 64]);
  }
  __syncthreads();

  f32x16 oacc[2];
  oacc[0] = (f32x16)0.f; oacc[1] = (f32x16)0.f;
  float lrun = 0.f;
  const int swzA = (l31 & 7) * 8;

  for (int jt = jk0; jt < jkn; ++jt) {
    const int jj = jt - jk0;
    const int cur = jj & 1;
    if (jt + 1 < jkn) {  // async DMA next tile into the other buffer
      const int nb = cur ^ 1;
#pragma unroll
      for (int c = 0; c < 2; ++c) {
        const int rbase = w * 16 + c * 8;
        const int row = rbase + rc;
        const int gc = (sgr ^ (row & 7)) * 8;
        gload16(Kb + hb + (size_t)((jt + 1) * 64 + row) * D_ + gc,
                &Ks[nb][rbase * 64]);
        gload16(Vtb + hb + (size_t)row * T_ + (jt + 1) * 64 + gc,
                &Vs[nb][rbase * 64]);
      }
    }

    if (jt * 64 <= qwmax) {
      // ---- S phase (scores in log2 domain; Q pre-scaled) ----
      f32x16 sacc[2];
      sacc[0] = (f32x16)0.f; sacc[1] = (f32x16)0.f;
      __builtin_amdgcn_s_setprio(1);
#pragma unroll
      for (int kc = 0; kc < 2; ++kc)
#pragma unroll
        for (int cs = 0; cs < 4; ++cs) {
          bf16x8 kf = *(const bf16x8*)
              &Ks[cur][(kc * 32 + l31) * 64 + ((cs * 16 + 8 * hi) ^ swzA)];
          sacc[kc] = __builtin_amdgcn_mfma_f32_32x32x16_bf16(kf, qf[cs], sacc[kc], 0, 0, 0);
        }
      __builtin_amdgcn_s_setprio(0);

      // ---- softmax-lite: P = exp2(s), fixed max ----
      float ps[32];
      if ((jt + 1) * 64 > qw0) {  // diagonal region: element mask
#pragma unroll
        for (int kc = 0; kc < 2; ++kc)
#pragma unroll
          for (int r = 0; r < 16; ++r) {
            const int kglob = jt * 64 + kc * 32 + (r & 3) + 8 * (r >> 2) + 4 * hi;
            ps[kc * 16 + r] = __builtin_amdgcn_exp2f(
                kglob > qrow ? -1e30f : sacc[kc][r]);
          }
      } else {
#pragma unroll
        for (int kc = 0; kc < 2; ++kc)
#pragma unroll
          for (int r = 0; r < 16; ++r)
            ps[kc * 16 + r] = __builtin_amdgcn_exp2f(sacc[kc][r]);
      }

      // tree sum
      float sm[16];
#pragma unroll
      for (int i = 0; i < 16; ++i) sm[i] = ps[i] + ps[i + 16];
#pragma unroll
      for (int i = 0; i < 8; ++i) sm[i] = sm[i] + sm[i + 8];
#pragma unroll
      for (int i = 0; i < 4; ++i) sm[i] = sm[i] + sm[i + 4];
      float rs = (sm[0] + sm[1]) + (sm[2] + sm[3]);
      rs += __shfl_xor(rs, 32);
      lrun += rs;

      // P -> bf16 B-frags, register-local
      u32 pw[4][4];
#pragma unroll
      for (int ks = 0; ks < 4; ++ks)
#pragma unroll
        for (int wd = 0; wd < 4; ++wd)
          pw[ks][wd] = pkcvt(ps[(ks >> 1) * 16 + (ks & 1) * 8 + 2 * wd],
                             ps[(ks >> 1) * 16 + (ks & 1) * 8 + 2 * wd + 1]);

      // ---- O phase ----
      __builtin_amdgcn_s_setprio(1);
#pragma unroll
      for (int dc = 0; dc < 2; ++dc) {
#pragma unroll
        for (int ks = 0; ks < 4; ++ks) {
          const int rb = (dc * 32 + l31) * 64;
          bf16x4 v0 = *(const bf16x4*)&Vs[cur][rb + ((ks * 16 + 4 * hi) ^ swzA)];
          bf16x4 v1 = *(const bf16x4*)&Vs[cur][rb + ((ks * 16 + 4 * hi + 8) ^ swzA)];
          bf16x8 vf;
          *(bf16x4*)&vf = v0; *((bf16x4*)&vf + 1) = v1;
          bf16x8 pf;
          *(uint4*)&pf = make_uint4(pw[ks][0], pw[ks][1], pw[ks][2], pw[ks][3]);
          oacc[dc] = __builtin_amdgcn_mfma_f32_32x32x16_bf16(vf, pf, oacc[dc], 0, 0, 0);
        }
      }
      __builtin_amdgcn_s_setprio(0);
    }

    __syncthreads();  // compute(jt) done everywhere + DMA(jt+1) drained
  }

  u16* obase = attnb + ((size_t)(b * T_ + qrow)) * C_ + h * 64;

  if (!is_split) {
    const float inv = 1.0f / lrun;
#pragma unroll
    for (int dc = 0; dc < 2; ++dc)
#pragma unroll
      for (int g4 = 0; g4 < 4; ++g4) {
        uint2 o;
        o.x = pkcvt(oacc[dc][g4 * 4 + 0] * inv, oacc[dc][g4 * 4 + 1] * inv);
        o.y = pkcvt(oacc[dc][g4 * 4 + 2] * inv, oacc[dc][g4 * 4 + 3] * inv);
        *(uint2*)(obase + dc * 32 + 8 * g4 + 4 * hi) = o;
      }
  } else {
    // write OWN slot only; combine_kernel merges after kernel boundary
    const int qt = bh * 8 + (qb - 8);
    const int halfid = (jk0 > 0) ? 1 : 0;
    const int qloc = w * 32 + l31;
    u16* mypart = halfid ? (Opart + ((size_t)qt * 128 + qloc) * 64) : obase;
#pragma unroll
    for (int dc = 0; dc < 2; ++dc)
#pragma unroll
      for (int g4 = 0; g4 < 4; ++g4) {
        uint2 o;
        o.x = pkcvt(oacc[dc][g4 * 4 + 0], oacc[dc][g4 * 4 + 1]);
        o.y = pkcvt(oacc[dc][g4 * 4 + 2], oacc[dc][g4 * 4 + 3]);
        *(uint2*)(mypart + dc * 32 + 8 * g4 + 4 * hi) = o;
      }
    if (hi == 0) lpart[(qt * 2 + halfid) * 128 + qloc] = lrun;
  }
}

// ---------------------------------------------------------------------------
// Combine: for each split q-tile, attnb_slice = (attnb_slice + Opart) / (l0+l1)
// 384 blocks x 256 threads; thread = (row, col-half of 32). uint4 = 8 bf16
// per iteration x 4 iterations = all 32 cols (R16 bug: uint2 covered only 16).
// ---------------------------------------------------------------------------
__global__ __launch_bounds__(256) void combine_kernel(
    u16* __restrict__ attnb, const u16* __restrict__ Opart,
    const float* __restrict__ lpart) {
  const int qt = blockIdx.x;               // 48 bh * 8 qb-high
  const int bh = qt >> 3, qb = (qt & 7) + 8;
  const int b = bh / H_, h = bh % H_;
  const int row = threadIdx.x >> 1;        // 0..127
  const int ch = (threadIdx.x & 1) * 32;   // col half
  const int qrow = qb * 128 + row;
  u16* obase = attnb + ((size_t)(b * T_ + qrow)) * C_ + h * 64 + ch;
  const u16* p1 = Opart + ((size_t)qt * 128 + row) * 64 + ch;
  const float inv =
      1.0f / (lpart[(qt * 2 + 0) * 128 + row] + lpart[(qt * 2 + 1) * 128 + row]);
#pragma unroll
  for (int j = 0; j < 4; ++j) {
    uint4 a = *(const uint4*)(obase + j * 8);
    uint4 c = *(const uint4*)(p1 + j * 8);
    const float s0 = bflo(a.x) + bflo(c.x), s1 = bfhi(a.x) + bfhi(c.x);
    const float s2 = bflo(a.y) + bflo(c.y), s3 = bfhi(a.y) + bfhi(c.y);
    const float s4 = bflo(a.z) + bflo(c.z), s5 = bfhi(a.z) + bfhi(c.z);
    const float s6 = bflo(a.w) + bflo(c.w), s7 = bfhi(a.w) + bfhi(c.w);
    uint4 o;
    o.x = pkcvt(s0 * inv, s1 * inv);
    o.y = pkcvt(s2 * inv, s3 * inv);
    o.z = pkcvt(s4 * inv, s5 * inv);
    o.w = pkcvt(s6 * inv, s7 * inv);
    *(uint4*)(obase + j * 8) = o;
  }
}

// ---------------------------------------------------------------------------
extern "C" void kernel_launch(void* const* d_in, const int* in_sizes, int n_in,
                              void* d_out, int out_size, void* d_ws, size_t ws_size,
                              hipStream_t stream) {
  (void)in_sizes; (void)n_in; (void)out_size; (void)ws_size;
  const float* x  = (const float*)d_in[0];
  const float* Wq = (const float*)d_in[1];
  const float* Wk = (const float*)d_in[2];
  const float* Wv = (const float*)d_in[3];
  const float* Wp = (const float*)d_in[4];
  const float* bp = (const float*)d_in[5];
  float* out = (float*)d_out;

  // ws (u16 units): Wt | Wpt | Qb | Kb | Vtb | R (xb then attnb) | Opart |
  // lpart. ~58.2 MB total (< 64.1 MB proven envelope from R1).
  u16* Wt    = (u16*)d_ws;
  u16* Wpt   = Wt + 442368;
  u16* Qb    = Wpt + 147456;
  u16* Kb    = Qb + 6291456;
  u16* Vtb   = Kb + 6291456;
  u16* R     = Vtb + 6291456;
  u16* xb    = R;
  u16* attnb = R;
  u16* Opart = R + 6291456;                 // 384*128*64 u16
  float* lpart = (float*)(Opart + 3145728); // 384*2*128 f32

  xcvt_kernel<<<3072, 256, 0, stream>>>(x, xb);
  convert_kernel<<<576, 256, 0, stream>>>(Wq, Wk, Wv, Wp, Wt, Wpt);
  gemm_qkv<<<1152, 256, 0, stream>>>(xb, Wt, Qb, Kb, Vtb);
  attn_mfma_kernel<<<1152, 256, 0, stream>>>(Qb, Kb, Vtb, attnb, Opart, lpart);
  combine_kernel<<<384, 256, 0, stream>>>(attnb, Opart, lpart);
  gemm_proj<<<384, 256, 0, stream>>>(attnb, Wpt, bp, out);
}

// Round 18
// 121.187 us; speedup vs baseline: 2.3510x; 1.0014x over previous
//
#include <hip/hip_runtime.h>
#include <hip/hip_bf16.h>

// B=8, T=2048, C=384, H=6, Dh=64
constexpr int T_ = 2048;
constexpr int C_ = 384;
constexpr int H_ = 6;
constexpr int D_ = 64;

typedef unsigned int u32;
typedef unsigned short u16;
typedef __attribute__((ext_vector_type(4))) float f32x4;
typedef __attribute__((ext_vector_type(16))) float f32x16;
typedef __attribute__((ext_vector_type(8))) short bf16x8;
typedef __attribute__((ext_vector_type(4))) short bf16x4;

__device__ __forceinline__ u32 f2bf(float f) {
  u32 u = __float_as_uint(f);
  return (u + 0x7FFFu + ((u >> 16) & 1u)) >> 16;  // RNE
}
__device__ __forceinline__ u32 pk2(float a, float b) {
  return f2bf(a) | (f2bf(b) << 16);
}
__device__ __forceinline__ float bflo(u32 u) { return __uint_as_float(u << 16); }
__device__ __forceinline__ float bfhi(u32 u) { return __uint_as_float(u & 0xFFFF0000u); }
// packed f32->bf16x2 (v_cvt_pk_bf16_f32)
__device__ __forceinline__ u32 pkcvt(float a, float b) {
  __hip_bfloat162 h = __float22bfloat162_rn(float2{a, b});
  return *(u32*)&h;
}
// async global->LDS DMA, 16B per lane; lds dest = wave-uniform base + lane*16
__device__ __forceinline__ void gload16(const u16* g, u16* l) {
  __builtin_amdgcn_global_load_lds(
      (const __attribute__((address_space(1))) u32*)g,
      (__attribute__((address_space(3))) u32*)l, 16, 0, 0);
}

constexpr float SC_ = 0.18033688011112042f;  // 0.125 * log2(e)

// Job tables (LPT, per-bh 24 jobs): qb>=8 split in two k-chunks.
__device__ const int JQB[24] = {15,15, 7,14,14,13,13, 6,12,12,11,11, 5,10,10, 9, 9, 4, 8, 8, 3, 2, 1, 0};
__device__ const int JK0[24] = { 0,16, 0, 0,15, 0,14, 0, 0,13, 0,12, 0, 0,11, 0,10, 0, 0, 9, 0, 0, 0, 0};
__device__ const int JKN[24] = {16,32,16,15,30,14,28,14,13,26,12,24,12,11,22,10,20,10, 9,18, 8, 6, 4, 2};

// ---------------------------------------------------------------------------
// x fp32 -> bf16 row-major [16384][384]
// ---------------------------------------------------------------------------
__global__ __launch_bounds__(256) void xcvt_kernel(
    const float* __restrict__ x, u16* __restrict__ xb) {
  const int id = blockIdx.x * 256 + threadIdx.x;  // 786432 threads x 8 elems
  const float* s = x + (size_t)id * 8;
  f32x4 a = *(const f32x4*)s, b = *(const f32x4*)(s + 4);
  uint4 o;
  o.x = pkcvt(a[0], a[1]); o.y = pkcvt(a[2], a[3]);
  o.z = pkcvt(b[0], b[1]); o.w = pkcvt(b[2], b[3]);
  *(uint4*)(xb + (size_t)id * 8) = o;
}

// ---------------------------------------------------------------------------
// Weights -> bf16 transposed [n][k]
// ---------------------------------------------------------------------------
__global__ __launch_bounds__(256) void convert_kernel(
    const float* __restrict__ Wq, const float* __restrict__ Wk,
    const float* __restrict__ Wv, const float* __restrict__ Wp,
    u16* __restrict__ Wt, u16* __restrict__ Wpt) {
  int id = blockIdx.x * 256 + threadIdx.x;
  if (id < 110592) {                       // Wt: 1152*384/4
    int n = id / 96, c0 = (id % 96) * 4;
    int mat = n / 384, nn = n % 384, h = nn >> 6, d = nn & 63;
    const float* W = (mat == 0) ? Wq : ((mat == 1) ? Wk : Wv);
    const float* s = W + (size_t)(h * C_ + c0) * D_ + d;
    uint2 o; o.x = pk2(s[0], s[64]); o.y = pk2(s[128], s[192]);
    *(uint2*)&Wt[(size_t)n * 384 + c0] = o;
  } else {                                 // Wpt: 384*384/4
    int id2 = id - 110592;
    int n = id2 / 96, c0 = (id2 % 96) * 4;
    const float* s = Wp + (size_t)c0 * C_ + n;
    uint2 o; o.x = pk2(s[0], s[384]); o.y = pk2(s[768], s[1152]);
    *(uint2*)&Wpt[(size_t)n * 384 + c0] = o;
  }
}

// ===========================================================================
// m97-structure 128x128 bf16 GEMM core (HW-proven 874 TF on gfx950)
// ===========================================================================
#define GEMM_BODY(A_PTR, B_PTR)                                                \
  __shared__ u16 As[128 * 64], Bs[128 * 64];                                   \
  const int tid = threadIdx.x;                                                 \
  const int l = tid & 63, w = tid >> 6;                                        \
  const int wr = w >> 1, wc = w & 1;                                           \
  const int ql = l & 15, g = l >> 4;                                           \
  const int rc = l >> 3;   /* row within an 8-row DMA call */                  \
  const int sgr = l & 7;   /* LDS slot granule this lane fills */              \
  f32x4 acc[4][4];                                                             \
  _Pragma("unroll") for (int fi = 0; fi < 4; ++fi)                             \
  _Pragma("unroll") for (int fj = 0; fj < 4; ++fj) acc[fi][fj] = (f32x4)0.f;   \
  for (int kc = 0; kc < 6; ++kc) {                                             \
    if (kc) __syncthreads();                                                   \
    _Pragma("unroll") for (int c = 0; c < 4; ++c) {                            \
      const int rbase = w * 32 + c * 8;                                        \
      const int row = rbase + rc;                                              \
      const int gcol = (sgr ^ (row & 7)) * 8; /* inverse-swizzled source */    \
      gload16((A_PTR) + (size_t)(m0 + row) * 384 + kc * 64 + gcol,             \
              &As[rbase * 64]);                                                \
      gload16((B_PTR) + (size_t)(n0 + row) * 384 + kc * 64 + gcol,             \
              &Bs[rbase * 64]);                                                \
    }                                                                          \
    __syncthreads(); /* compiler drains vmcnt before barrier */                \
    __builtin_amdgcn_s_setprio(1);                                             \
    _Pragma("unroll") for (int ks = 0; ks < 2; ++ks) {                         \
      bf16x8 af[4], bfr_[4];                                                   \
      const int gl = ks * 4 + g;                                               \
      const int slot8 = (gl ^ (ql & 7)) * 8;                                   \
      _Pragma("unroll") for (int fi = 0; fi < 4; ++fi)                         \
        af[fi] = *(const bf16x8*)&As[(wr * 64 + fi * 16 + ql) * 64 + slot8];   \
      _Pragma("unroll") for (int fj = 0; fj < 4; ++fj)                         \
        bfr_[fj] = *(const bf16x8*)&Bs[(wc * 64 + fj * 16 + ql) * 64 + slot8]; \
      _Pragma("unroll") for (int fi = 0; fi < 4; ++fi)                         \
      _Pragma("unroll") for (int fj = 0; fj < 4; ++fj)                         \
        acc[fi][fj] = __builtin_amdgcn_mfma_f32_16x16x32_bf16(                 \
            af[fi], bfr_[fj], acc[fi][fj], 0, 0, 0);                           \
    }                                                                          \
    __builtin_amdgcn_s_setprio(0);                                             \
  }

// ---------------------------------------------------------------------------
// QKV GEMM: xb [16384][384] @ Wt [1152][384] -> Qb/Kb [B,H,T,D], Vtb [B,H,D,T]
// ---------------------------------------------------------------------------
__global__ __launch_bounds__(256) void gemm_qkv(
    const u16* __restrict__ xb, const u16* __restrict__ Wt,
    u16* __restrict__ Qb, u16* __restrict__ Kb, u16* __restrict__ Vtb) {
  const int bx = blockIdx.x;
  const int mt = bx / 9, nt = bx % 9;
  const int m0 = mt * 128, n0 = nt * 128;

  GEMM_BODY(xb, Wt)

  const int mat = nt / 3;
#pragma unroll
  for (int fi = 0; fi < 4; ++fi) {
    const int m = m0 + wr * 64 + fi * 16 + g * 4;
    const int b = m >> 11, t = m & 2047;
#pragma unroll
    for (int fj = 0; fj < 4; ++fj) {
      const int n = n0 + wc * 64 + fj * 16 + ql;
      const int nn = n - mat * 384, h = nn >> 6, d = nn & 63;
      if (mat == 0) {
        u16* dst = Qb + ((size_t)(b * H_ + h) * T_ + t) * D_ + d;
#pragma unroll
        for (int r = 0; r < 4; ++r)
          dst[(size_t)r * D_] = (u16)f2bf(acc[fi][fj][r] * SC_);
      } else if (mat == 1) {
        u16* dst = Kb + ((size_t)(b * H_ + h) * T_ + t) * D_ + d;
#pragma unroll
        for (int r = 0; r < 4; ++r) dst[(size_t)r * D_] = (u16)f2bf(acc[fi][fj][r]);
      } else {  // V transposed [B,H,D,T]
        u16* dst = Vtb + ((size_t)(b * H_ + h) * D_ + d) * T_ + t;
        uint2 o;
        o.x = pkcvt(acc[fi][fj][0], acc[fi][fj][1]);
        o.y = pkcvt(acc[fi][fj][2], acc[fi][fj][3]);
        *(uint2*)dst = o;
      }
    }
  }
}

// ---------------------------------------------------------------------------
// Output projection GEMM: attnb [16384][384] @ Wpt [384][384] + bp -> out fp32
// ---------------------------------------------------------------------------
__global__ __launch_bounds__(256) void gemm_proj(
    const u16* __restrict__ attnb, const u16* __restrict__ Wpt,
    const float* __restrict__ bp, float* __restrict__ out) {
  const int bx = blockIdx.x;
  const int mt = bx / 3, nt = bx % 3;
  const int m0 = mt * 128, n0 = nt * 128;

  GEMM_BODY(attnb, Wpt)

#pragma unroll
  for (int fj = 0; fj < 4; ++fj) {
    const int n = n0 + wc * 64 + fj * 16 + ql;
    const float bias = bp[n];
#pragma unroll
    for (int fi = 0; fi < 4; ++fi) {
      const int m = m0 + wr * 64 + fi * 16 + g * 4;
#pragma unroll
      for (int r = 0; r < 4; ++r)
        out[(size_t)(m + r) * C_ + n] = acc[fi][fj][r] + bias;
    }
  }
}

// ---------------------------------------------------------------------------
// Flash attention, split-K balanced jobs, XCD-AFFINE grid: all 24 jobs of a
// given bh land on ONE XCD (bh % 8 == bx & 7 under round-robin dispatch), so
// that bh's K/V (512 KB; 6 bh = 3 MB < 4 MB) stays L2-resident across its
// 16-24 blocks — the kernel was L3-BW-bound on 428 MB of K/V re-reads (R17).
// LPT rank-major within each XCD. Combine via separate kernel (no fences).
// ---------------------------------------------------------------------------
__global__ __launch_bounds__(256) void attn_mfma_kernel(
    const u16* __restrict__ Qb, const u16* __restrict__ Kb,
    const u16* __restrict__ Vtb, u16* __restrict__ attnb,
    u16* __restrict__ Opart, float* __restrict__ lpart) {
  __shared__ u16 Ks[2][64 * 64];
  __shared__ u16 Vs[2][64 * 64];
  const int tid = threadIdx.x;
  const int bx = blockIdx.x;
  // XCD-affine decode: bx = (rank*6 + bhi)*8 + xcd ; bh = bhi*8 + xcd
  const int xcd = bx & 7;
  const int j = bx >> 3;                   // 0..143
  const int rank = j / 6;                  // LPT: big jobs first per XCD
  const int bhi = j % 6;
  const int bh = bhi * 8 + xcd;
  const int qb = JQB[rank];
  const int jk0 = JK0[rank], jkn = JKN[rank];
  const bool is_split = (qb >= 8);
  const int h = bh % H_, b = bh / H_;
  const int Q0 = qb * 128;
  const size_t hb = (size_t)bh * T_ * D_;

  const int l = tid & 63, w = tid >> 6;
  const int hi = l >> 5, l31 = l & 31;
  const int qw0 = Q0 + w * 32;
  const int qrow = qw0 + l31;
  const int qwmax = qw0 + 31;
  const int rc = l >> 3;   // row within an 8-row DMA call
  const int sgr = l & 7;   // LDS granule this lane fills

  bf16x8 qf[4];
  {
    const u16* qg = Qb + hb + (size_t)qrow * D_ + hi * 8;
#pragma unroll
    for (int cs = 0; cs < 4; ++cs) qf[cs] = *(const bf16x8*)(qg + cs * 16);
  }

  // prologue: DMA tile jk0 -> buf 0
#pragma unroll
  for (int c = 0; c < 2; ++c) {
    const int rbase = w * 16 + c * 8;
    const int row = rbase + rc;
    const int gc = (sgr ^ (row & 7)) * 8;
    gload16(Kb + hb + (size_t)(jk0 * 64 + row) * D_ + gc, &Ks[0][rbase * 64]);
    gload16(Vtb + hb + (size_t)row * T_ + jk0 * 64 + gc, &Vs[0][rbase * 64]);
  }
  __syncthreads();

  f32x16 oacc[2];
  oacc[0] = (f32x16)0.f; oacc[1] = (f32x16)0.f;
  float lrun = 0.f;
  const int swzA = (l31 & 7) * 8;

  for (int jt = jk0; jt < jkn; ++jt) {
    const int jj = jt - jk0;
    const int cur = jj & 1;
    if (jt + 1 < jkn) {  // async DMA next tile into the other buffer
      const int nb = cur ^ 1;
#pragma unroll
      for (int c = 0; c < 2; ++c) {
        const int rbase = w * 16 + c * 8;
        const int row = rbase + rc;
        const int gc = (sgr ^ (row & 7)) * 8;
        gload16(Kb + hb + (size_t)((jt + 1) * 64 + row) * D_ + gc,
                &Ks[nb][rbase * 64]);
        gload16(Vtb + hb + (size_t)row * T_ + (jt + 1) * 64 + gc,
                &Vs[nb][rbase * 64]);
      }
    }

    if (jt * 64 <= qwmax) {
      // ---- S phase (scores in log2 domain; Q pre-scaled) ----
      f32x16 sacc[2];
      sacc[0] = (f32x16)0.f; sacc[1] = (f32x16)0.f;
      __builtin_amdgcn_s_setprio(1);
#pragma unroll
      for (int kc = 0; kc < 2; ++kc)
#pragma unroll
        for (int cs = 0; cs < 4; ++cs) {
          bf16x8 kf = *(const bf16x8*)
              &Ks[cur][(kc * 32 + l31) * 64 + ((cs * 16 + 8 * hi) ^ swzA)];
          sacc[kc] = __builtin_amdgcn_mfma_f32_32x32x16_bf16(kf, qf[cs], sacc[kc], 0, 0, 0);
        }
      __builtin_amdgcn_s_setprio(0);

      // ---- softmax-lite: P = exp2(s), fixed max ----
      float ps[32];
      if ((jt + 1) * 64 > qw0) {  // diagonal region: element mask
#pragma unroll
        for (int kc = 0; kc < 2; ++kc)
#pragma unroll
          for (int r = 0; r < 16; ++r) {
            const int kglob = jt * 64 + kc * 32 + (r & 3) + 8 * (r >> 2) + 4 * hi;
            ps[kc * 16 + r] = __builtin_amdgcn_exp2f(
                kglob > qrow ? -1e30f : sacc[kc][r]);
          }
      } else {
#pragma unroll
        for (int kc = 0; kc < 2; ++kc)
#pragma unroll
          for (int r = 0; r < 16; ++r)
            ps[kc * 16 + r] = __builtin_amdgcn_exp2f(sacc[kc][r]);
      }

      // tree sum
      float sm[16];
#pragma unroll
      for (int i = 0; i < 16; ++i) sm[i] = ps[i] + ps[i + 16];
#pragma unroll
      for (int i = 0; i < 8; ++i) sm[i] = sm[i] + sm[i + 8];
#pragma unroll
      for (int i = 0; i < 4; ++i) sm[i] = sm[i] + sm[i + 4];
      float rs = (sm[0] + sm[1]) + (sm[2] + sm[3]);
      rs += __shfl_xor(rs, 32);
      lrun += rs;

      // P -> bf16 B-frags, register-local
      u32 pw[4][4];
#pragma unroll
      for (int ks = 0; ks < 4; ++ks)
#pragma unroll
        for (int wd = 0; wd < 4; ++wd)
          pw[ks][wd] = pkcvt(ps[(ks >> 1) * 16 + (ks & 1) * 8 + 2 * wd],
                             ps[(ks >> 1) * 16 + (ks & 1) * 8 + 2 * wd + 1]);

      // ---- O phase ----
      __builtin_amdgcn_s_setprio(1);
#pragma unroll
      for (int dc = 0; dc < 2; ++dc) {
#pragma unroll
        for (int ks = 0; ks < 4; ++ks) {
          const int rb = (dc * 32 + l31) * 64;
          bf16x4 v0 = *(const bf16x4*)&Vs[cur][rb + ((ks * 16 + 4 * hi) ^ swzA)];
          bf16x4 v1 = *(const bf16x4*)&Vs[cur][rb + ((ks * 16 + 4 * hi + 8) ^ swzA)];
          bf16x8 vf;
          *(bf16x4*)&vf = v0; *((bf16x4*)&vf + 1) = v1;
          bf16x8 pf;
          *(uint4*)&pf = make_uint4(pw[ks][0], pw[ks][1], pw[ks][2], pw[ks][3]);
          oacc[dc] = __builtin_amdgcn_mfma_f32_32x32x16_bf16(vf, pf, oacc[dc], 0, 0, 0);
        }
      }
      __builtin_amdgcn_s_setprio(0);
    }

    __syncthreads();  // compute(jt) done everywhere + DMA(jt+1) drained
  }

  u16* obase = attnb + ((size_t)(b * T_ + qrow)) * C_ + h * 64;

  if (!is_split) {
    const float inv = 1.0f / lrun;
#pragma unroll
    for (int dc = 0; dc < 2; ++dc)
#pragma unroll
      for (int g4 = 0; g4 < 4; ++g4) {
        uint2 o;
        o.x = pkcvt(oacc[dc][g4 * 4 + 0] * inv, oacc[dc][g4 * 4 + 1] * inv);
        o.y = pkcvt(oacc[dc][g4 * 4 + 2] * inv, oacc[dc][g4 * 4 + 3] * inv);
        *(uint2*)(obase + dc * 32 + 8 * g4 + 4 * hi) = o;
      }
  } else {
    // write OWN slot only; combine_kernel merges after kernel boundary
    const int qt = bh * 8 + (qb - 8);
    const int halfid = (jk0 > 0) ? 1 : 0;
    const int qloc = w * 32 + l31;
    u16* mypart = halfid ? (Opart + ((size_t)qt * 128 + qloc) * 64) : obase;
#pragma unroll
    for (int dc = 0; dc < 2; ++dc)
#pragma unroll
      for (int g4 = 0; g4 < 4; ++g4) {
        uint2 o;
        o.x = pkcvt(oacc[dc][g4 * 4 + 0], oacc[dc][g4 * 4 + 1]);
        o.y = pkcvt(oacc[dc][g4 * 4 + 2], oacc[dc][g4 * 4 + 3]);
        *(uint2*)(mypart + dc * 32 + 8 * g4 + 4 * hi) = o;
      }
    if (hi == 0) lpart[(qt * 2 + halfid) * 128 + qloc] = lrun;
  }
}

// ---------------------------------------------------------------------------
// Combine: attnb_slice = (attnb_slice + Opart) / (l0+l1). uint4 = 8 bf16 per
// iteration x 4 = all 32 cols per thread-half.
// ---------------------------------------------------------------------------
__global__ __launch_bounds__(256) void combine_kernel(
    u16* __restrict__ attnb, const u16* __restrict__ Opart,
    const float* __restrict__ lpart) {
  const int qt = blockIdx.x;               // 48 bh * 8 qb-high
  const int bh = qt >> 3, qb = (qt & 7) + 8;
  const int b = bh / H_, h = bh % H_;
  const int row = threadIdx.x >> 1;        // 0..127
  const int ch = (threadIdx.x & 1) * 32;   // col half
  const int qrow = qb * 128 + row;
  u16* obase = attnb + ((size_t)(b * T_ + qrow)) * C_ + h * 64 + ch;
  const u16* p1 = Opart + ((size_t)qt * 128 + row) * 64 + ch;
  const float inv =
      1.0f / (lpart[(qt * 2 + 0) * 128 + row] + lpart[(qt * 2 + 1) * 128 + row]);
#pragma unroll
  for (int j = 0; j < 4; ++j) {
    uint4 a = *(const uint4*)(obase + j * 8);
    uint4 c = *(const uint4*)(p1 + j * 8);
    const float s0 = bflo(a.x) + bflo(c.x), s1 = bfhi(a.x) + bfhi(c.x);
    const float s2 = bflo(a.y) + bflo(c.y), s3 = bfhi(a.y) + bfhi(c.y);
    const float s4 = bflo(a.z) + bflo(c.z), s5 = bfhi(a.z) + bfhi(c.z);
    const float s6 = bflo(a.w) + bflo(c.w), s7 = bfhi(a.w) + bfhi(c.w);
    uint4 o;
    o.x = pkcvt(s0 * inv, s1 * inv);
    o.y = pkcvt(s2 * inv, s3 * inv);
    o.z = pkcvt(s4 * inv, s5 * inv);
    o.w = pkcvt(s6 * inv, s7 * inv);
    *(uint4*)(obase + j * 8) = o;
  }
}

// ---------------------------------------------------------------------------
extern "C" void kernel_launch(void* const* d_in, const int* in_sizes, int n_in,
                              void* d_out, int out_size, void* d_ws, size_t ws_size,
                              hipStream_t stream) {
  (void)in_sizes; (void)n_in; (void)out_size; (void)ws_size;
  const float* x  = (const float*)d_in[0];
  const float* Wq = (const float*)d_in[1];
  const float* Wk = (const float*)d_in[2];
  const float* Wv = (const float*)d_in[3];
  const float* Wp = (const float*)d_in[4];
  const float* bp = (const float*)d_in[5];
  float* out = (float*)d_out;

  u16* Wt    = (u16*)d_ws;
  u16* Wpt   = Wt + 442368;
  u16* Qb    = Wpt + 147456;
  u16* Kb    = Qb + 6291456;
  u16* Vtb   = Kb + 6291456;
  u16* R     = Vtb + 6291456;
  u16* xb    = R;
  u16* attnb = R;
  u16* Opart = R + 6291456;                 // 384*128*64 u16
  float* lpart = (float*)(Opart + 3145728); // 384*2*128 f32

  xcvt_kernel<<<3072, 256, 0, stream>>>(x, xb);
  convert_kernel<<<576, 256, 0, stream>>>(Wq, Wk, Wv, Wp, Wt, Wpt);
  gemm_qkv<<<1152, 256, 0, stream>>>(xb, Wt, Qb, Kb, Vtb);
  attn_mfma_kernel<<<1152, 256, 0, stream>>>(Qb, Kb, Vtb, attnb, Opart, lpart);
  combine_kernel<<<384, 256, 0, stream>>>(attnb, Opart, lpart);
  gemm_proj<<<384, 256, 0, stream>>>(attnb, Wpt, bp, out);
}

// Round 19
// 118.529 us; speedup vs baseline: 2.4038x; 1.0224x over previous
//
#include <hip/hip_runtime.h>
#include <hip/hip_bf16.h>

// B=8, T=2048, C=384, H=6, Dh=64
constexpr int T_ = 2048;
constexpr int C_ = 384;
constexpr int H_ = 6;
constexpr int D_ = 64;

typedef unsigned int u32;
typedef unsigned short u16;
typedef __attribute__((ext_vector_type(4))) float f32x4;
typedef __attribute__((ext_vector_type(16))) float f32x16;
typedef __attribute__((ext_vector_type(8))) short bf16x8;
typedef __attribute__((ext_vector_type(4))) short bf16x4;

__device__ __forceinline__ u32 f2bf(float f) {
  u32 u = __float_as_uint(f);
  return (u + 0x7FFFu + ((u >> 16) & 1u)) >> 16;  // RNE
}
__device__ __forceinline__ u32 pk2(float a, float b) {
  return f2bf(a) | (f2bf(b) << 16);
}
// packed f32->bf16x2 (v_cvt_pk_bf16_f32)
__device__ __forceinline__ u32 pkcvt(float a, float b) {
  __hip_bfloat162 h = __float22bfloat162_rn(float2{a, b});
  return *(u32*)&h;
}
// async global->LDS DMA, 16B per lane; lds dest = wave-uniform base + lane*16
__device__ __forceinline__ void gload16(const u16* g, u16* l) {
  __builtin_amdgcn_global_load_lds(
      (const __attribute__((address_space(1))) u32*)g,
      (__attribute__((address_space(3))) u32*)l, 16, 0, 0);
}

constexpr float SC_ = 0.18033688011112042f;  // 0.125 * log2(e)

// ---------------------------------------------------------------------------
// x fp32 -> bf16 row-major [16384][384]
// ---------------------------------------------------------------------------
__global__ __launch_bounds__(256) void xcvt_kernel(
    const float* __restrict__ x, u16* __restrict__ xb) {
  const int id = blockIdx.x * 256 + threadIdx.x;  // 786432 threads x 8 elems
  const float* s = x + (size_t)id * 8;
  f32x4 a = *(const f32x4*)s, b = *(const f32x4*)(s + 4);
  uint4 o;
  o.x = pkcvt(a[0], a[1]); o.y = pkcvt(a[2], a[3]);
  o.z = pkcvt(b[0], b[1]); o.w = pkcvt(b[2], b[3]);
  *(uint4*)(xb + (size_t)id * 8) = o;
}

// ---------------------------------------------------------------------------
// Weights -> bf16 transposed [n][k]
// ---------------------------------------------------------------------------
__global__ __launch_bounds__(256) void convert_kernel(
    const float* __restrict__ Wq, const float* __restrict__ Wk,
    const float* __restrict__ Wv, const float* __restrict__ Wp,
    u16* __restrict__ Wt, u16* __restrict__ Wpt) {
  int id = blockIdx.x * 256 + threadIdx.x;
  if (id < 110592) {                       // Wt: 1152*384/4
    int n = id / 96, c0 = (id % 96) * 4;
    int mat = n / 384, nn = n % 384, h = nn >> 6, d = nn & 63;
    const float* W = (mat == 0) ? Wq : ((mat == 1) ? Wk : Wv);
    const float* s = W + (size_t)(h * C_ + c0) * D_ + d;
    uint2 o; o.x = pk2(s[0], s[64]); o.y = pk2(s[128], s[192]);
    *(uint2*)&Wt[(size_t)n * 384 + c0] = o;
  } else {                                 // Wpt: 384*384/4
    int id2 = id - 110592;
    int n = id2 / 96, c0 = (id2 % 96) * 4;
    const float* s = Wp + (size_t)c0 * C_ + n;
    uint2 o; o.x = pk2(s[0], s[384]); o.y = pk2(s[768], s[1152]);
    *(uint2*)&Wpt[(size_t)n * 384 + c0] = o;
  }
}

// ===========================================================================
// m97-structure 128x128 bf16 GEMM core (HW-proven 874 TF on gfx950)
// ===========================================================================
#define GEMM_BODY(A_PTR, B_PTR)                                                \
  __shared__ u16 As[128 * 64], Bs[128 * 64];                                   \
  const int tid = threadIdx.x;                                                 \
  const int l = tid & 63, w = tid >> 6;                                        \
  const int wr = w >> 1, wc = w & 1;                                           \
  const int ql = l & 15, g = l >> 4;                                           \
  const int rc = l >> 3;   /* row within an 8-row DMA call */                  \
  const int sgr = l & 7;   /* LDS slot granule this lane fills */              \
  f32x4 acc[4][4];                                                             \
  _Pragma("unroll") for (int fi = 0; fi < 4; ++fi)                             \
  _Pragma("unroll") for (int fj = 0; fj < 4; ++fj) acc[fi][fj] = (f32x4)0.f;   \
  for (int kc = 0; kc < 6; ++kc) {                                             \
    if (kc) __syncthreads();                                                   \
    _Pragma("unroll") for (int c = 0; c < 4; ++c) {                            \
      const int rbase = w * 32 + c * 8;                                        \
      const int row = rbase + rc;                                              \
      const int gcol = (sgr ^ (row & 7)) * 8; /* inverse-swizzled source */    \
      gload16((A_PTR) + (size_t)(m0 + row) * 384 + kc * 64 + gcol,             \
              &As[rbase * 64]);                                                \
      gload16((B_PTR) + (size_t)(n0 + row) * 384 + kc * 64 + gcol,             \
              &Bs[rbase * 64]);                                                \
    }                                                                          \
    __syncthreads(); /* compiler drains vmcnt before barrier */                \
    __builtin_amdgcn_s_setprio(1);                                             \
    _Pragma("unroll") for (int ks = 0; ks < 2; ++ks) {                         \
      bf16x8 af[4], bfr_[4];                                                   \
      const int gl = ks * 4 + g;                                               \
      const int slot8 = (gl ^ (ql & 7)) * 8;                                   \
      _Pragma("unroll") for (int fi = 0; fi < 4; ++fi)                         \
        af[fi] = *(const bf16x8*)&As[(wr * 64 + fi * 16 + ql) * 64 + slot8];   \
      _Pragma("unroll") for (int fj = 0; fj < 4; ++fj)                         \
        bfr_[fj] = *(const bf16x8*)&Bs[(wc * 64 + fj * 16 + ql) * 64 + slot8]; \
      _Pragma("unroll") for (int fi = 0; fi < 4; ++fi)                         \
      _Pragma("unroll") for (int fj = 0; fj < 4; ++fj)                         \
        acc[fi][fj] = __builtin_amdgcn_mfma_f32_16x16x32_bf16(                 \
            af[fi], bfr_[fj], acc[fi][fj], 0, 0, 0);                           \
    }                                                                          \
    __builtin_amdgcn_s_setprio(0);                                             \
  }

// ---------------------------------------------------------------------------
// QKV GEMM: xb [16384][384] @ Wt [1152][384] -> Qb/Kb [B,H,T,D], Vtb [B,H,D,T]
// ---------------------------------------------------------------------------
__global__ __launch_bounds__(256) void gemm_qkv(
    const u16* __restrict__ xb, const u16* __restrict__ Wt,
    u16* __restrict__ Qb, u16* __restrict__ Kb, u16* __restrict__ Vtb) {
  const int bx = blockIdx.x;
  const int mt = bx / 9, nt = bx % 9;
  const int m0 = mt * 128, n0 = nt * 128;

  GEMM_BODY(xb, Wt)

  const int mat = nt / 3;
#pragma unroll
  for (int fi = 0; fi < 4; ++fi) {
    const int m = m0 + wr * 64 + fi * 16 + g * 4;
    const int b = m >> 11, t = m & 2047;
#pragma unroll
    for (int fj = 0; fj < 4; ++fj) {
      const int n = n0 + wc * 64 + fj * 16 + ql;
      const int nn = n - mat * 384, h = nn >> 6, d = nn & 63;
      if (mat == 0) {
        u16* dst = Qb + ((size_t)(b * H_ + h) * T_ + t) * D_ + d;
#pragma unroll
        for (int r = 0; r < 4; ++r)
          dst[(size_t)r * D_] = (u16)f2bf(acc[fi][fj][r] * SC_);
      } else if (mat == 1) {
        u16* dst = Kb + ((size_t)(b * H_ + h) * T_ + t) * D_ + d;
#pragma unroll
        for (int r = 0; r < 4; ++r) dst[(size_t)r * D_] = (u16)f2bf(acc[fi][fj][r]);
      } else {  // V transposed [B,H,D,T]
        u16* dst = Vtb + ((size_t)(b * H_ + h) * D_ + d) * T_ + t;
        uint2 o;
        o.x = pkcvt(acc[fi][fj][0], acc[fi][fj][1]);
        o.y = pkcvt(acc[fi][fj][2], acc[fi][fj][3]);
        *(uint2*)dst = o;
      }
    }
  }
}

// ---------------------------------------------------------------------------
// Output projection GEMM: attnb [16384][384] @ Wpt [384][384] + bp -> out fp32
// ---------------------------------------------------------------------------
__global__ __launch_bounds__(256) void gemm_proj(
    const u16* __restrict__ attnb, const u16* __restrict__ Wpt,
    const float* __restrict__ bp, float* __restrict__ out) {
  const int bx = blockIdx.x;
  const int mt = bx / 3, nt = bx % 3;
  const int m0 = mt * 128, n0 = nt * 128;

  GEMM_BODY(attnb, Wpt)

#pragma unroll
  for (int fj = 0; fj < 4; ++fj) {
    const int n = n0 + wc * 64 + fj * 16 + ql;
    const float bias = bp[n];
#pragma unroll
    for (int fi = 0; fi < 4; ++fi) {
      const int m = m0 + wr * 64 + fi * 16 + g * 4;
#pragma unroll
      for (int r = 0; r < 4; ++r)
        out[(size_t)(m + r) * C_ + n] = acc[fi][fj][r] + bias;
    }
  }
}

// ---------------------------------------------------------------------------
// Flash attention, QBLOCK=256 (8 waves x 32 q-rows, 512 threads): halves the
// K/V re-read traffic (428 -> 221 MB), the surviving bottleneck theory after
// schedule/split/affinity variants all measured 66-72 us. Per-wave compute
// identical to R14; staging = 1 K + 1 V DMA call per wave per tile; one
// barrier per tile (drain certifies DMA + read-completion). LPT heavy-first.
// ---------------------------------------------------------------------------
__global__ __launch_bounds__(512) void attn_mfma_kernel(
    const u16* __restrict__ Qb, const u16* __restrict__ Kb,
    const u16* __restrict__ Vtb, u16* __restrict__ attnb) {
  __shared__ u16 Ks[2][64 * 64];
  __shared__ u16 Vs[2][64 * 64];
  const int tid = threadIdx.x;
  const int bx = blockIdx.x;
  const int qb = 7 - (bx / 48);            // heavy-first (LPT)
  const int bh = bx % 48;
  const int h = bh % H_, b = bh / H_;
  const int Q0 = qb * 256;
  const int nt = 4 * qb + 4;
  const size_t hb = (size_t)bh * T_ * D_;

  const int l = tid & 63, w = tid >> 6;    // 8 waves
  const int hi = l >> 5, l31 = l & 31;
  const int qw0 = Q0 + w * 32;
  const int qrow = qw0 + l31;
  const int qwmax = qw0 + 31;
  const int rc = l >> 3;   // row within the wave's 8-row DMA slice
  const int sgr = l & 7;   // LDS granule this lane fills
  const int srow = w * 8 + rc;             // tile row this lane stages
  const int sgc = (sgr ^ (srow & 7)) * 8;  // inverse-swizzled source granule

  bf16x8 qf[4];
  {
    const u16* qg = Qb + hb + (size_t)qrow * D_ + hi * 8;
#pragma unroll
    for (int cs = 0; cs < 4; ++cs) qf[cs] = *(const bf16x8*)(qg + cs * 16);
  }

  // prologue: DMA tile 0 -> buf 0 (wave w stages rows w*8 .. w*8+7)
  gload16(Kb + hb + (size_t)srow * D_ + sgc, &Ks[0][(w * 8) * 64]);
  gload16(Vtb + hb + (size_t)srow * T_ + sgc, &Vs[0][(w * 8) * 64]);
  __syncthreads();

  f32x16 oacc[2];
  oacc[0] = (f32x16)0.f; oacc[1] = (f32x16)0.f;
  float lrun = 0.f;
  const int swzA = (l31 & 7) * 8;

  for (int jt = 0; jt < nt; ++jt) {
    const int cur = jt & 1;
    if (jt + 1 < nt) {  // async DMA next tile into the other buffer
      const int nb = cur ^ 1;
      gload16(Kb + hb + (size_t)((jt + 1) * 64 + srow) * D_ + sgc,
              &Ks[nb][(w * 8) * 64]);
      gload16(Vtb + hb + (size_t)srow * T_ + (jt + 1) * 64 + sgc,
              &Vs[nb][(w * 8) * 64]);
    }

    if (jt * 64 <= qwmax) {
      // ---- S phase (scores in log2 domain; Q pre-scaled) ----
      f32x16 sacc[2];
      sacc[0] = (f32x16)0.f; sacc[1] = (f32x16)0.f;
      __builtin_amdgcn_s_setprio(1);
#pragma unroll
      for (int kc = 0; kc < 2; ++kc)
#pragma unroll
        for (int cs = 0; cs < 4; ++cs) {
          bf16x8 kf = *(const bf16x8*)
              &Ks[cur][(kc * 32 + l31) * 64 + ((cs * 16 + 8 * hi) ^ swzA)];
          sacc[kc] = __builtin_amdgcn_mfma_f32_32x32x16_bf16(kf, qf[cs], sacc[kc], 0, 0, 0);
        }
      __builtin_amdgcn_s_setprio(0);

      // ---- softmax-lite: P = exp2(s), fixed max ----
      float ps[32];
      if ((jt + 1) * 64 > qw0) {  // diagonal region: element mask
#pragma unroll
        for (int kc = 0; kc < 2; ++kc)
#pragma unroll
          for (int r = 0; r < 16; ++r) {
            const int kglob = jt * 64 + kc * 32 + (r & 3) + 8 * (r >> 2) + 4 * hi;
            ps[kc * 16 + r] = __builtin_amdgcn_exp2f(
                kglob > qrow ? -1e30f : sacc[kc][r]);
          }
      } else {
#pragma unroll
        for (int kc = 0; kc < 2; ++kc)
#pragma unroll
          for (int r = 0; r < 16; ++r)
            ps[kc * 16 + r] = __builtin_amdgcn_exp2f(sacc[kc][r]);
      }

      // tree sum
      float sm[16];
#pragma unroll
      for (int i = 0; i < 16; ++i) sm[i] = ps[i] + ps[i + 16];
#pragma unroll
      for (int i = 0; i < 8; ++i) sm[i] = sm[i] + sm[i + 8];
#pragma unroll
      for (int i = 0; i < 4; ++i) sm[i] = sm[i] + sm[i + 4];
      float rs = (sm[0] + sm[1]) + (sm[2] + sm[3]);
      rs += __shfl_xor(rs, 32);
      lrun += rs;

      // P -> bf16 B-frags, register-local
      u32 pw[4][4];
#pragma unroll
      for (int ks = 0; ks < 4; ++ks)
#pragma unroll
        for (int wd = 0; wd < 4; ++wd)
          pw[ks][wd] = pkcvt(ps[(ks >> 1) * 16 + (ks & 1) * 8 + 2 * wd],
                             ps[(ks >> 1) * 16 + (ks & 1) * 8 + 2 * wd + 1]);

      // ---- O phase ----
      __builtin_amdgcn_s_setprio(1);
#pragma unroll
      for (int dc = 0; dc < 2; ++dc) {
#pragma unroll
        for (int ks = 0; ks < 4; ++ks) {
          const int rb = (dc * 32 + l31) * 64;
          bf16x4 v0 = *(const bf16x4*)&Vs[cur][rb + ((ks * 16 + 4 * hi) ^ swzA)];
          bf16x4 v1 = *(const bf16x4*)&Vs[cur][rb + ((ks * 16 + 4 * hi + 8) ^ swzA)];
          bf16x8 vf;
          *(bf16x4*)&vf = v0; *((bf16x4*)&vf + 1) = v1;
          bf16x8 pf;
          *(uint4*)&pf = make_uint4(pw[ks][0], pw[ks][1], pw[ks][2], pw[ks][3]);
          oacc[dc] = __builtin_amdgcn_mfma_f32_32x32x16_bf16(vf, pf, oacc[dc], 0, 0, 0);
        }
      }
      __builtin_amdgcn_s_setprio(0);
    }

    __syncthreads();  // compute(jt) done everywhere + DMA(jt+1) drained
  }

  const float inv = 1.0f / lrun;
  u16* obase = attnb + ((size_t)(b * T_ + qrow)) * C_ + h * 64;
#pragma unroll
  for (int dc = 0; dc < 2; ++dc)
#pragma unroll
    for (int g4 = 0; g4 < 4; ++g4) {
      uint2 o;
      o.x = pkcvt(oacc[dc][g4 * 4 + 0] * inv, oacc[dc][g4 * 4 + 1] * inv);
      o.y = pkcvt(oacc[dc][g4 * 4 + 2] * inv, oacc[dc][g4 * 4 + 3] * inv);
      *(uint2*)(obase + dc * 32 + 8 * g4 + 4 * hi) = o;
    }
}

// ---------------------------------------------------------------------------
extern "C" void kernel_launch(void* const* d_in, const int* in_sizes, int n_in,
                              void* d_out, int out_size, void* d_ws, size_t ws_size,
                              hipStream_t stream) {
  (void)in_sizes; (void)n_in; (void)out_size; (void)ws_size;
  const float* x  = (const float*)d_in[0];
  const float* Wq = (const float*)d_in[1];
  const float* Wk = (const float*)d_in[2];
  const float* Wv = (const float*)d_in[3];
  const float* Wp = (const float*)d_in[4];
  const float* bp = (const float*)d_in[5];
  float* out = (float*)d_out;

  // ws (u16 units): Wt | Wpt | Qb | Kb | Vtb | R (xb then attnb, disjoint).
  u16* Wt    = (u16*)d_ws;
  u16* Wpt   = Wt + 442368;
  u16* Qb    = Wpt + 147456;
  u16* Kb    = Qb + 6291456;
  u16* Vtb   = Kb + 6291456;
  u16* R     = Vtb + 6291456;
  u16* xb    = R;
  u16* attnb = R;

  xcvt_kernel<<<3072, 256, 0, stream>>>(x, xb);
  convert_kernel<<<576, 256, 0, stream>>>(Wq, Wk, Wv, Wp, Wt, Wpt);
  gemm_qkv<<<1152, 256, 0, stream>>>(xb, Wt, Qb, Kb, Vtb);
  attn_mfma_kernel<<<384, 512, 0, stream>>>(Qb, Kb, Vtb, attnb);
  gemm_proj<<<384, 256, 0, stream>>>(attnb, Wpt, bp, out);
}